// Round 14
// baseline (2557.016 us; speedup 1.0000x reference)
//
#include <hip/hip_runtime.h>
#include <hip/hip_bf16.h>

typedef __bf16 bf16x8 __attribute__((ext_vector_type(8)));
typedef __bf16 bf16x4 __attribute__((ext_vector_type(4)));
typedef float  f32x4  __attribute__((ext_vector_type(4)));

static constexpr int BB   = 1024;
static constexpr int INF  = 256;
static constexpr int LATF = 512;
static constexpr int HIDF = 1024;
static constexpr int OUTF = 64;
static constexpr float DT = 0.05f;

// normal cached staging (weights/x)
__device__ __forceinline__ void gload_lds16(const __bf16* g, __bf16* l) {
    __builtin_amdgcn_global_load_lds(
        (const __attribute__((address_space(1))) void*)g,
        (__attribute__((address_space(3))) void*)l, 16, 0, 0);
}

// exchange staging: l2 -> sc0 (shared XCD L2); fallback -> sc0|sc1 (IF)
__device__ __forceinline__ void gload_lds16_x(const void* g, void* l, bool l2) {
    if (l2)
        __builtin_amdgcn_global_load_lds(
            (const __attribute__((address_space(1))) void*)g,
            (__attribute__((address_space(3))) void*)l, 16, 0, 1);
    else
        __builtin_amdgcn_global_load_lds(
            (const __attribute__((address_space(1))) void*)g,
            (__attribute__((address_space(3))) void*)l, 16, 0, 17);
}

__device__ __forceinline__ void store_f32x4_x(float* p, f32x4 v, bool l2) {
    if (l2) asm volatile("global_store_dwordx4 %0, %1, off sc0" :: "v"(p), "v"(v) : "memory");
    else    asm volatile("global_store_dwordx4 %0, %1, off sc0 sc1" :: "v"(p), "v"(v) : "memory");
}

// f32 atomic add: l2 mode -> local TCC (same-XCD coherent); fallback -> device scope
__device__ __forceinline__ void atom_add_x(float* p, float v, bool l2) {
    if (l2) asm volatile("global_atomic_add_f32 %0, %1, off" :: "v"(p), "v"(v) : "memory");
    else    asm volatile("global_atomic_add_f32 %0, %1, off sc1" :: "v"(p), "v"(v) : "memory");
}

__device__ __forceinline__ void drain_vmem() {
    asm volatile("s_waitcnt vmcnt(0)" ::: "memory");
}

__device__ __forceinline__ unsigned atomic_peek_l2(unsigned* p) {
    unsigned v, zero = 0;
    asm volatile("global_atomic_add %0, %1, %2, off sc0\n\ts_waitcnt vmcnt(0)"
                 : "=v"(v) : "v"(p), "v"(zero) : "memory");
    return v;
}

__device__ __forceinline__ void post_x(unsigned* p, bool l2) {
    if (l2) {
        unsigned one = 1u;
        asm volatile("global_atomic_add %0, %1, off" :: "v"(p), "v"(one) : "memory");
    } else {
        __hip_atomic_fetch_add(p, 1u, __ATOMIC_RELAXED, __HIP_MEMORY_SCOPE_AGENT);
    }
}

__device__ __forceinline__ void spin_ge_t0(unsigned* p, unsigned tgt, bool l2) {
    int guard = 0;
    if (l2) {
        while (atomic_peek_l2(p) < tgt) {
            __builtin_amdgcn_s_sleep(1);
            if (++guard > (1 << 16)) break;
        }
    } else {
        while (__hip_atomic_load(p, __ATOMIC_RELAXED, __HIP_MEMORY_SCOPE_AGENT) < tgt) {
            __builtin_amdgcn_s_sleep(1);
            if (++guard > (1 << 20)) break;
        }
    }
}

__device__ __forceinline__ float tanh_fast(float x) {
    float e = __expf(2.0f * x);
    return (e - 1.0f) / (e + 1.0f);
}

// ---------------- fused prep: x->bf16 + 3 weight transposes ----------------
__global__ __launch_bounds__(256)
void prep_k(const float* __restrict__ x, __bf16* __restrict__ xb,
            const float* __restrict__ W_in, __bf16* __restrict__ WinT,
            const float* __restrict__ W1, __bf16* __restrict__ W1T,
            const float* __restrict__ W2, __bf16* __restrict__ W2T) {
    const int b = blockIdx.x;
    const int tx = threadIdx.x, ty = threadIdx.y;
    if (b < 256) {
        const int i = b * 256 + ty * 32 + tx;
        float4 v = reinterpret_cast<const float4*>(x)[i];
        bf16x4 o;
        o[0] = (__bf16)v.x; o[1] = (__bf16)v.y; o[2] = (__bf16)v.z; o[3] = (__bf16)v.w;
        reinterpret_cast<bf16x4*>(xb)[i] = o;
        return;
    }
    const float* src; __bf16* dst; int R, C, tb;
    if (b < 384)      { src = W_in; dst = WinT; R = 256;  C = 512;  tb = b - 256; }
    else if (b < 896) { src = W1;   dst = W1T;  R = 512;  C = 1024; tb = b - 384; }
    else              { src = W2;   dst = W2T;  R = 1024; C = 512;  tb = b - 896; }
    __shared__ float tile[32][33];
    const int nbc = C / 32;
    const int c0 = (tb % nbc) * 32, r0 = (tb / nbc) * 32;
#pragma unroll
    for (int i = 0; i < 32; i += 8)
        tile[ty + i][tx] = src[(size_t)(r0 + ty + i) * C + (c0 + tx)];
    __syncthreads();
#pragma unroll
    for (int i = 0; i < 32; i += 8)
        dst[(size_t)(c0 + ty + i) * R + (r0 + tx)] = (__bf16)tile[tx][ty + i];
}

// ---- persistent ODE: ONE sync/dyn. z is WG-LOCAL; G1 via K-split f32 atomics ----
// (round-13 design; this round fixes the LDS-pointer-array static-initializer
// compile error — Fb[2] array replaced by scalar F0/F1 + ternary select.)
__global__ __launch_bounds__(256, 1)
void ode_persist(const __bf16* __restrict__ xb, const __bf16* __restrict__ WinT,
                 const __bf16* __restrict__ W1T, const __bf16* __restrict__ W2T,
                 const float* __restrict__ b_in, const float* __restrict__ b1,
                 const float* __restrict__ wlast, const float* __restrict__ b2,
                 float* __restrict__ gacc, float* __restrict__ hG,
                 unsigned* __restrict__ flags) {
    // LDS: F32 dbuf 2x32KB | G bf16 [32][1024] 64KB | SCR 8KB | Z 4KB
    __shared__ __align__(16) unsigned char SL[143392];
    unsigned char* const F0 = SL;
    unsigned char* const F1 = SL + 32768;
    unsigned char* const G   = SL + 65536;
    unsigned char* const SCR = SL + 131072;
    unsigned char* const Z   = SL + 139264;
    __shared__ int sh_l2ok;

    const int bid   = blockIdx.x;
    const int rb    = (bid & 7) * 4 + ((bid >> 3) & 3);  // slices of rb share bid%8
    const int slice = bid >> 5;
    const int r0 = rb * 32;
    const int c1 = slice * 128;   // zero-pass col share
    const int c2 = slice * 64;    // owned LAT cols

    unsigned* czp = flags + rb * 32;

    const int tid  = threadIdx.x;
    const int w    = tid >> 6;
    const int lane = tid & 63;
    const int fr   = lane & 15;
    const int kq   = lane >> 4;
    const int cw   = w & 1;
    const int kw   = w >> 1;

    // ---- measured same-L2 verification (round-8 verbatim) ----
    if (tid == 0) {
        unsigned* cvp   = flags + 1024;
        unsigned* cvp2  = flags + 1056;
        unsigned* trial = flags + 2048 + rb * 32;
        unsigned* vis   = flags + 4096;
        unsigned* okb   = flags + 12288;
        const unsigned magic = 0xC0DE0000u | (unsigned)bid;
        asm volatile("global_store_dword %0, %1, off sc0" :: "v"(&vis[bid * 32]), "v"(magic) : "memory");
        drain_vmem();
        __hip_atomic_fetch_add(cvp, 1u, __ATOMIC_RELAXED, __HIP_MEMORY_SCOPE_AGENT);
        { int g = 0; while (__hip_atomic_load(cvp, __ATOMIC_RELAXED, __HIP_MEMORY_SCOPE_AGENT) < 256u) { __builtin_amdgcn_s_sleep(1); if (++g > (1 << 20)) break; } }
        unsigned ok = 1;
        for (int s = 0; s < 8; ++s) {
            const int pb = (rb >> 2) + 8 * (rb & 3) + 32 * s;
            unsigned v;
            asm volatile("global_load_dword %0, %1, off sc0\n\ts_waitcnt vmcnt(0)"
                         : "=v"(v) : "v"(&vis[pb * 32]) : "memory");
            ok &= (v == (0xC0DE0000u | (unsigned)pb)) ? 1u : 0u;
        }
        {
            unsigned one = 1u;
            asm volatile("global_atomic_add %0, %1, off" :: "v"(trial), "v"(one) : "memory");
            int g = 0;
            while (atomic_peek_l2(trial) < 8u) {
                __builtin_amdgcn_s_sleep(1);
                if (++g > (1 << 15)) { ok = 0; break; }
            }
        }
        asm volatile("global_store_dword %0, %1, off sc0 sc1" :: "v"(&okb[bid * 32]), "v"(ok) : "memory");
        drain_vmem();
        __hip_atomic_fetch_add(cvp2, 1u, __ATOMIC_RELAXED, __HIP_MEMORY_SCOPE_AGENT);
        { int g = 0; while (__hip_atomic_load(cvp2, __ATOMIC_RELAXED, __HIP_MEMORY_SCOPE_AGENT) < 256u) { __builtin_amdgcn_s_sleep(1); if (++g > (1 << 20)) break; } }
        unsigned allok = 1;
        for (int s = 0; s < 8; ++s) {
            const int pb = (rb >> 2) + 8 * (rb & 3) + 32 * s;
            unsigned v;
            asm volatile("global_load_dword %0, %1, off sc0 sc1\n\ts_waitcnt vmcnt(0)"
                         : "=v"(v) : "v"(&okb[pb * 32]) : "memory");
            allok &= v;
        }
        sh_l2ok = (int)allok;
    }
    __syncthreads();
    const bool l2m = (sh_l2ok != 0);

    // ---- persistent register weights ----
    bf16x8 b1r[8][2][2];  // G1-partial B: col = nc*128 + w*32 + 16n + fr, k-slice c2..+63
#pragma unroll
    for (int nc = 0; nc < 8; ++nc)
#pragma unroll
        for (int n = 0; n < 2; ++n)
#pragma unroll
            for (int ks = 0; ks < 2; ++ks)
                b1r[nc][n][ks] = *reinterpret_cast<const bf16x8*>(
                    W1T + (size_t)(nc * 128 + w * 32 + 16 * n + fr) * 512 +
                    c2 + ks * 32 + kq * 8);

    bf16x8 b2r[2][16];  // G2 B: col = c2 + cw*32 + 16n + fr, k-half kw*512
#pragma unroll
    for (int n = 0; n < 2; ++n)
#pragma unroll
        for (int ks = 0; ks < 16; ++ks)
            b2r[n][ks] = *reinterpret_cast<const bf16x8*>(
                W2T + (size_t)(c2 + cw * 32 + 16 * n + fr) * 1024 +
                kw * 512 + ks * 32 + kq * 8);

    float b2v[2], binv[2];
#pragma unroll
    for (int n = 0; n < 2; ++n) {
        const int colk = c2 + cw * 32 + 16 * n + fr;
        b2v[n]  = b2[colk];
        binv[n] = b_in[colk];
    }
    const int tc = tid * 4;
    const float4 b1q = *reinterpret_cast<const float4*>(b1 + tc);
    const float4 wlq = *reinterpret_cast<const float4*>(wlast + tc);

    f32x4 hr[2][2], ha[2][2];  // valid on kw==0 waves

    const size_t rbStride = 32 * 1024;
    auto bufPtr = [&](int buf) { return gacc + ((size_t)buf * 32 + rb) * rbStride; };

    // G1-partial from Z -> atomic adds into target buffer
    auto G1P = [&](float* gadd) {
        bf16x8 a2[2][2];
#pragma unroll
        for (int mi = 0; mi < 2; ++mi)
#pragma unroll
            for (int ks = 0; ks < 2; ++ks) {
                const int rowA = 16 * mi + fr;
                const int gz = ks * 4 + kq;
                a2[mi][ks] = *reinterpret_cast<const bf16x8*>(
                    Z + (size_t)rowA * 128 + ((gz ^ (rowA & 7)) << 4));
            }
#pragma unroll
        for (int nc = 0; nc < 8; ++nc) {
            f32x4 a[2][2];
#pragma unroll
            for (int mi = 0; mi < 2; ++mi)
#pragma unroll
                for (int n = 0; n < 2; ++n) a[mi][n] = f32x4{0.f, 0.f, 0.f, 0.f};
#pragma unroll
            for (int ks = 0; ks < 2; ++ks)
#pragma unroll
                for (int mi = 0; mi < 2; ++mi)
#pragma unroll
                    for (int n = 0; n < 2; ++n)
                        a[mi][n] = __builtin_amdgcn_mfma_f32_16x16x32_bf16(
                            a2[mi][ks], b1r[nc][n][ks], a[mi][n], 0, 0, 0);
#pragma unroll
            for (int mi = 0; mi < 2; ++mi)
#pragma unroll
                for (int n = 0; n < 2; ++n) {
                    const int col = nc * 128 + w * 32 + 16 * n + fr;
#pragma unroll
                    for (int j = 0; j < 4; ++j)
                        atom_add_x(gadd + (size_t)(16 * mi + kq * 4 + j) * 1024 + col,
                                   a[mi][n][j], l2m);
                }
        }
    };

    // write z (bf16) into Z LDS, swizzled (kw==0 waves)
    auto zwrite = [&](int mi, int n, int j, float v) {
        const int row = 16 * mi + kq * 4 + j;
        const int col = cw * 32 + 16 * n + fr;
        const int gc = col >> 3;
        *reinterpret_cast<__bf16*>(Z + (size_t)row * 128 + ((gc ^ (row & 7)) << 4) +
                                   (col & 7) * 2) = (__bf16)v;
    };

    // =========== h0 = tanh(x @ W_in + b_in) ===========
    {
#pragma unroll
        for (int i = 0; i < 4; ++i) {
            const int idx = w * 4 + i;
            const int row = idx * 2 + (lane >> 5);
            const int gam = (lane & 31) ^ (row & 7);
            gload_lds16(xb + (size_t)(r0 + row) * 256 + gam * 8,
                        (__bf16*)(F0 + (size_t)idx * 1024));
        }
        bf16x8 winr[2][4];
#pragma unroll
        for (int n = 0; n < 2; ++n)
#pragma unroll
            for (int ks = 0; ks < 4; ++ks)
                winr[n][ks] = *reinterpret_cast<const bf16x8*>(
                    WinT + (size_t)(c2 + cw * 32 + 16 * n + fr) * 256 +
                    kw * 128 + ks * 32 + kq * 8);
        __syncthreads();

        f32x4 acc[2][2];
#pragma unroll
        for (int mi = 0; mi < 2; ++mi)
#pragma unroll
            for (int n = 0; n < 2; ++n) acc[mi][n] = f32x4{0.f, 0.f, 0.f, 0.f};
#pragma unroll
        for (int ks = 0; ks < 4; ++ks) {
            bf16x8 a[2];
#pragma unroll
            for (int mi = 0; mi < 2; ++mi) {
                const int rowA = 16 * mi + fr;
                const int gk = kw * 16 + ks * 4 + kq;
                a[mi] = *reinterpret_cast<const bf16x8*>(
                    F0 + (size_t)rowA * 512 + ((gk ^ (rowA & 7)) << 4));
            }
#pragma unroll
            for (int mi = 0; mi < 2; ++mi)
#pragma unroll
                for (int n = 0; n < 2; ++n)
                    acc[mi][n] = __builtin_amdgcn_mfma_f32_16x16x32_bf16(a[mi], winr[n][ks],
                                                                         acc[mi][n], 0, 0, 0);
        }
        __syncthreads();
        if (kw == 1) {
#pragma unroll
            for (int mi = 0; mi < 2; ++mi)
#pragma unroll
                for (int n = 0; n < 2; ++n)
                    *reinterpret_cast<f32x4*>(SCR + cw * 4096 + ((mi * 2 + n) * 64 + lane) * 16) =
                        acc[mi][n];
        }
        __syncthreads();
        if (kw == 0) {
#pragma unroll
            for (int mi = 0; mi < 2; ++mi)
#pragma unroll
                for (int n = 0; n < 2; ++n) {
                    f32x4 part = *reinterpret_cast<const f32x4*>(
                        SCR + cw * 4096 + ((mi * 2 + n) * 64 + lane) * 16);
#pragma unroll
                    for (int j = 0; j < 4; ++j) {
                        const float v = tanh_fast(acc[mi][n][j] + part[j] + binv[n]);
                        hr[mi][n][j] = v;
                        zwrite(mi, n, j, v);
                    }
                }
        }
        __syncthreads();          // Z visible to all waves
        G1P(bufPtr(0));           // adds for dyn 0
        drain_vmem();
        __syncthreads();
        if (tid == 0) post_x(czp, l2m);
    }

    // =========== 80 dyn evaluations ===========
    for (int it = 0; it < 80; ++it) {
        const int s4 = it >> 2, st = it & 3;
        const float t = DT * (float)s4 + ((st == 0) ? 0.f : (st == 3) ? DT : 0.5f * DT);

        if (tid == 0) spin_ge_t0(czp, 8u * (unsigned)(it + 1), l2m);
        __syncthreads();

        // ---- stage gacc[it%3] in 8-row quarters (double-buffered) + tanh -> G ----
        const float* src = bufPtr(it % 3);
        {
#pragma unroll
            for (int i = 0; i < 8; ++i)
                gload_lds16_x(src + (size_t)(i * 256 + tid) * 4,
                              F0 + (size_t)(i * 256 + tid) * 16, l2m);
            int cur = 0;
            for (int q = 0; q < 4; ++q) {
                __syncthreads();  // quarter q staged
                if (q < 3) {
                    unsigned char* nb = (cur ^ 1) ? F1 : F0;
#pragma unroll
                    for (int i = 0; i < 8; ++i)
                        gload_lds16_x(src + (size_t)((q + 1) * 8192) + (size_t)(i * 256 + tid) * 4,
                                      nb + (size_t)(i * 256 + tid) * 16, l2m);
                }
                unsigned char* cb = cur ? F1 : F0;
                const int gq = tid >> 1;
                const int bo = (tid & 1) * 8;
#pragma unroll
                for (int r = 0; r < 8; ++r) {
                    f32x4 v = *reinterpret_cast<const f32x4*>(cb + (size_t)r * 4096 + tid * 16);
                    const int grow = q * 8 + r;
                    bf16x4 o;
                    o[0] = (__bf16)tanh_fast(v[0] + b1q.x + t * wlq.x);
                    o[1] = (__bf16)tanh_fast(v[1] + b1q.y + t * wlq.y);
                    o[2] = (__bf16)tanh_fast(v[2] + b1q.z + t * wlq.z);
                    o[3] = (__bf16)tanh_fast(v[3] + b1q.w + t * wlq.w);
                    *reinterpret_cast<bf16x4*>(
                        G + (size_t)grow * 2048 + ((gq ^ (grow & 7)) << 4) + bo) = o;
                }
                cur ^= 1;
            }
        }
        // zero-pass: my 128-col share of buf[(it+2)%3]
        if (it < 78) {
            float* zb = bufPtr((it + 2) % 3);
            const int zcol = c1 + (tid & 31) * 4;
            const f32x4 zz = {0.f, 0.f, 0.f, 0.f};
#pragma unroll
            for (int j = 0; j < 4; ++j)
                store_f32x4_x(zb + (size_t)((tid >> 5) * 4 + j) * 1024 + zcol, zz, l2m);
        }
        __syncthreads();  // G complete

        // ---- G2: k = g @ W2 + b2 ----
        f32x4 acc[2][2];
#pragma unroll
        for (int mi = 0; mi < 2; ++mi)
#pragma unroll
            for (int n = 0; n < 2; ++n) acc[mi][n] = f32x4{0.f, 0.f, 0.f, 0.f};
#pragma unroll
        for (int ks = 0; ks < 16; ++ks) {
            bf16x8 a[2];
#pragma unroll
            for (int mi = 0; mi < 2; ++mi) {
                const int rowA = 16 * mi + fr;
                const int gk = kw * 64 + ks * 4 + kq;
                a[mi] = *reinterpret_cast<const bf16x8*>(
                    G + (size_t)rowA * 2048 + ((gk ^ (rowA & 7)) << 4));
            }
#pragma unroll
            for (int mi = 0; mi < 2; ++mi)
#pragma unroll
                for (int n = 0; n < 2; ++n)
                    acc[mi][n] = __builtin_amdgcn_mfma_f32_16x16x32_bf16(a[mi], b2r[n][ks],
                                                                         acc[mi][n], 0, 0, 0);
        }
        __syncthreads();
        if (kw == 1) {
#pragma unroll
            for (int mi = 0; mi < 2; ++mi)
#pragma unroll
                for (int n = 0; n < 2; ++n)
                    *reinterpret_cast<f32x4*>(SCR + cw * 4096 + ((mi * 2 + n) * 64 + lane) * 16) =
                        acc[mi][n];
        }
        __syncthreads();
        if (kw == 0) {
            const float wA = (st == 0 || st == 3) ? (DT / 6.0f) : (DT / 3.0f);
            const float cZ = (st < 2) ? (0.5f * DT) : DT;
#pragma unroll
            for (int mi = 0; mi < 2; ++mi)
#pragma unroll
                for (int n = 0; n < 2; ++n) {
                    f32x4 part = *reinterpret_cast<const f32x4*>(
                        SCR + cw * 4096 + ((mi * 2 + n) * 64 + lane) * 16);
#pragma unroll
                    for (int j = 0; j < 4; ++j) {
                        const float kv = acc[mi][n][j] + part[j] + b2v[n];
                        float zv;
                        if (st == 0) {
                            ha[mi][n][j] = hr[mi][n][j] + wA * kv;
                            zv = hr[mi][n][j] + cZ * kv;
                        } else if (st < 3) {
                            ha[mi][n][j] += wA * kv;
                            zv = hr[mi][n][j] + cZ * kv;
                        } else {
                            hr[mi][n][j] = ha[mi][n][j] + wA * kv;
                            zv = hr[mi][n][j];
                        }
                        zwrite(mi, n, j, zv);
                    }
                }
        }
        __syncthreads();  // Z visible

        if (it < 79) {
            G1P(bufPtr((it + 1) % 3));  // adds for dyn it+1
            drain_vmem();
            __syncthreads();
            if (tid == 0) post_x(czp, l2m);
        }
    }

    // final h -> global
    if (kw == 0) {
#pragma unroll
        for (int mi = 0; mi < 2; ++mi)
#pragma unroll
            for (int n = 0; n < 2; ++n)
#pragma unroll
                for (int j = 0; j < 4; ++j)
                    hG[(size_t)(r0 + 16 * mi + kq * 4 + j) * 512 +
                       (c2 + cw * 32 + 16 * n + fr)] = hr[mi][n][j];
    }
}

// ---------------- out = h[:, :256] @ W_out + b_out (fp32) ----------------
__global__ __launch_bounds__(256)
void out_k(const float* __restrict__ h, const float* __restrict__ Wout,
           const float* __restrict__ bout, float* __restrict__ out) {
    const int col = threadIdx.x & 63;
    const int rg  = threadIdx.x >> 6;
    const int r0  = blockIdx.x * 16 + rg * 4;
    float a0 = 0.f, a1 = 0.f, a2 = 0.f, a3 = 0.f;
    for (int k = 0; k < 256; ++k) {
        const float w = Wout[k * OUTF + col];
        a0 += h[(r0 + 0) * LATF + k] * w;
        a1 += h[(r0 + 1) * LATF + k] * w;
        a2 += h[(r0 + 2) * LATF + k] * w;
        a3 += h[(r0 + 3) * LATF + k] * w;
    }
    const float b = bout[col];
    out[(r0 + 0) * OUTF + col] = a0 + b;
    out[(r0 + 1) * OUTF + col] = a1 + b;
    out[(r0 + 2) * OUTF + col] = a2 + b;
    out[(r0 + 3) * OUTF + col] = a3 + b;
}

extern "C" void kernel_launch(void* const* d_in, const int* in_sizes, int n_in,
                              void* d_out, int out_size, void* d_ws, size_t ws_size,
                              hipStream_t stream) {
    const float* x     = (const float*)d_in[0];
    const float* W_in  = (const float*)d_in[1];
    const float* b_in  = (const float*)d_in[2];
    const float* W1    = (const float*)d_in[3];
    const float* b1    = (const float*)d_in[4];
    const float* W2    = (const float*)d_in[5];
    const float* b2    = (const float*)d_in[6];
    const float* W_out = (const float*)d_in[7];
    const float* b_out = (const float*)d_in[8];
    float* out = (float*)d_out;

    char* ws = (char*)d_ws;
    size_t off = 0;
    auto alloc = [&](size_t bytes) {
        void* p = ws + off;
        off += (bytes + 255) & ~(size_t)255;
        return p;
    };
    __bf16* xb   = (__bf16*)alloc((size_t)BB * INF * 2);
    __bf16* WinT = (__bf16*)alloc((size_t)LATF * INF * 2);
    __bf16* W1T  = (__bf16*)alloc((size_t)HIDF * LATF * 2);
    __bf16* W2T  = (__bf16*)alloc((size_t)LATF * HIDF * 2);
    float*  h    = (float*)alloc((size_t)BB * LATF * 4);
    float*  gacc = (float*)alloc((size_t)3 * 32 * 32 * 1024 * 4);  // 12 MB
    unsigned* flags = (unsigned*)alloc(98304);
    if (off > ws_size) return;

    (void)hipMemsetAsync(flags, 0, 98304, stream);
    (void)hipMemsetAsync(gacc, 0, (size_t)3 * 32 * 32 * 1024 * 4, stream);
    prep_k<<<1408, dim3(32, 8), 0, stream>>>(x, xb, W_in, WinT, W1, W1T, W2, W2T);

    const float* w1last = W1 + (size_t)LATF * HIDF;

    ode_persist<<<256, 256, 0, stream>>>(xb, WinT, W1T, W2T, b_in, b1, w1last, b2,
                                         gacc, h, flags);

    out_k<<<BB / 16, 256, 0, stream>>>(h, W_out, b_out, out);
}

// Round 15
// 1131.114 us; speedup vs baseline: 2.2606x; 2.2606x over previous
//
#include <hip/hip_runtime.h>
#include <hip/hip_bf16.h>

typedef __bf16 bf16x8 __attribute__((ext_vector_type(8)));
typedef __bf16 bf16x4 __attribute__((ext_vector_type(4)));
typedef float  f32x4  __attribute__((ext_vector_type(4)));

static constexpr int BB   = 1024;
static constexpr int INF  = 256;
static constexpr int LATF = 512;
static constexpr int HIDF = 1024;
static constexpr int OUTF = 64;
static constexpr float DT = 0.05f;

// normal cached staging (weights/x; producer is a prior dispatch)
__device__ __forceinline__ void gload_lds16(const __bf16* g, __bf16* l) {
    __builtin_amdgcn_global_load_lds(
        (const __attribute__((address_space(1))) void*)g,
        (__attribute__((address_space(3))) void*)l, 16, 0, 0);
}

// exchange staging: l2 mode -> aux=1 (sc0: bypass L1, read shared XCD L2);
// fallback -> aux=17 (sc0|sc1: bypass L1+L2, read IF) — round-5 proven.
__device__ __forceinline__ void gload_lds16_x(const __bf16* g, __bf16* l, bool l2) {
    if (l2)
        __builtin_amdgcn_global_load_lds(
            (const __attribute__((address_space(1))) void*)g,
            (__attribute__((address_space(3))) void*)l, 16, 0, 1);
    else
        __builtin_amdgcn_global_load_lds(
            (const __attribute__((address_space(1))) void*)g,
            (__attribute__((address_space(3))) void*)l, 16, 0, 17);
}

// exchange store: l2 mode -> sc0 (meets consumers at the shared XCD L2);
// fallback -> sc0 sc1 (write-through IF)
__device__ __forceinline__ void store_bf16_x(__bf16* p, float v, bool l2) {
    const __bf16 b = (__bf16)v;
    unsigned u;
    __builtin_memcpy(&u, &b, 2);
    if (l2)
        asm volatile("global_store_short %0, %1, off sc0" :: "v"(p), "v"(u) : "memory");
    else
        asm volatile("global_store_short %0, %1, off sc0 sc1" :: "v"(p), "v"(u) : "memory");
}

__device__ __forceinline__ void drain_vmem() {
    asm volatile("s_waitcnt vmcnt(0)" ::: "memory");
}

// l2-mode flag read THROUGH THE ATOMIC PATH (add 0, return old)
__device__ __forceinline__ unsigned atomic_peek_l2(unsigned* p) {
    unsigned v, zero = 0;
    asm volatile("global_atomic_add %0, %1, %2, off sc0\n\ts_waitcnt vmcnt(0)"
                 : "=v"(v) : "v"(p), "v"(zero) : "memory");
    return v;
}

// flag post: l2 mode -> plain atomic (local TCC); fallback -> IF agent atomic.
__device__ __forceinline__ void post_x(unsigned* p, bool l2) {
    if (l2) {
        unsigned one = 1u;
        asm volatile("global_atomic_add %0, %1, off" :: "v"(p), "v"(one) : "memory");
    } else {
        __hip_atomic_fetch_add(p, 1u, __ATOMIC_RELAXED, __HIP_MEMORY_SCOPE_AGENT);
    }
}

// single-thread cross-WG poll (short guards: fail-fast, never bench-timeout)
__device__ __forceinline__ void spin_ge_t0(unsigned* p, unsigned tgt, bool l2) {
    int guard = 0;
    if (l2) {
        while (atomic_peek_l2(p) < tgt) {
            __builtin_amdgcn_s_sleep(1);
            if (++guard > (1 << 16)) break;
        }
    } else {
        while (__hip_atomic_load(p, __ATOMIC_RELAXED, __HIP_MEMORY_SCOPE_AGENT) < tgt) {
            __builtin_amdgcn_s_sleep(1);
            if (++guard > (1 << 20)) break;
        }
    }
}

__device__ __forceinline__ float tanh_fast(float x) {
    float e = __expf(2.0f * x);
    return (e - 1.0f) / (e + 1.0f);
}

// ---------------- fused prep: x->bf16 + 3 weight transposes ----------------
__global__ __launch_bounds__(256)
void prep_k(const float* __restrict__ x, __bf16* __restrict__ xb,
            const float* __restrict__ W_in, __bf16* __restrict__ WinT,
            const float* __restrict__ W1, __bf16* __restrict__ W1T,
            const float* __restrict__ W2, __bf16* __restrict__ W2T) {
    const int b = blockIdx.x;
    const int tx = threadIdx.x, ty = threadIdx.y;
    if (b < 256) {
        const int i = b * 256 + ty * 32 + tx;
        float4 v = reinterpret_cast<const float4*>(x)[i];
        bf16x4 o;
        o[0] = (__bf16)v.x; o[1] = (__bf16)v.y; o[2] = (__bf16)v.z; o[3] = (__bf16)v.w;
        reinterpret_cast<bf16x4*>(xb)[i] = o;
        return;
    }
    const float* src; __bf16* dst; int R, C, tb;
    if (b < 384)      { src = W_in; dst = WinT; R = 256;  C = 512;  tb = b - 256; }
    else if (b < 896) { src = W1;   dst = W1T;  R = 512;  C = 1024; tb = b - 384; }
    else              { src = W2;   dst = W2T;  R = 1024; C = 512;  tb = b - 896; }
    __shared__ float tile[32][33];
    const int nbc = C / 32;
    const int c0 = (tb % nbc) * 32, r0 = (tb / nbc) * 32;
#pragma unroll
    for (int i = 0; i < 32; i += 8)
        tile[ty + i][tx] = src[(size_t)(r0 + ty + i) * C + (c0 + tx)];
    __syncthreads();
#pragma unroll
    for (int i = 0; i < 32; i += 8)
        dst[(size_t)(c0 + ty + i) * R + (r0 + tx)] = (__bf16)tile[tx][ty + i];
}

// ------- persistent ODE kernel: 256 WGs x 512 threads = TWO intra-WG chains -------
// Round-12 design (correctness-proven) + PINNED register budget: round 12's
// launch_bounds(512,1) let the allocator pick 128 VGPRs (4 waves/EU heuristic)
// against ~220 demand -> 341GB of spill traffic. amdgpu_waves_per_eu(2,2) pins
// allocation at the 256-reg / 2-waves-per-EU point (m69 cliff: 8 waves/CU).
// WG b hosts chain A (ch=0) and chain B (ch=1); chain = (rb, slice) with
// rb = (b&7)+8*b[3]+16*ch (32 rows), slice = b[7:4] (G1 cols slice*64..+63, G2
// cols slice*32..+31). 8 waves = 2/SIMD co-resident by construction: when chain
// A's waves spin, chain B's wave on the SAME SIMD issues MFMA/staging (m114).
// Chains share nothing; intra-chain LDS epoch barrier replaces __syncthreads.
// All 16 slices of an rb share bid&7 -> one XCD (runtime-MEASURED; IF fallback).
__global__ __launch_bounds__(512, 1) __attribute__((amdgpu_waves_per_eu(2, 2)))
void ode_persist(const __bf16* __restrict__ xb, const __bf16* __restrict__ WinT,
                 const __bf16* __restrict__ W1T, const __bf16* __restrict__ W2T,
                 const float* __restrict__ b_in, const float* __restrict__ b1,
                 const float* __restrict__ wlast, const float* __restrict__ b2,
                 __bf16* __restrict__ zG, __bf16* __restrict__ gG,
                 float* __restrict__ hG, unsigned* __restrict__ flags) {
    __shared__ __align__(16) unsigned char SL[81920];  // 2 x (32KB tile + 4KB scratch + ctrs)

    const int tid  = threadIdx.x;
    const int ch   = tid >> 8;        // chain 0/1
    const int ctid = tid & 255;       // thread-in-chain
    const int w    = ctid >> 6;       // wave-in-chain 0..3
    const int lane = tid & 63;
    unsigned char* CB   = SL + ch * 40960;
    unsigned char* SCR  = CB + 32768;
    unsigned*      bcnt = (unsigned*)(CB + 36864);
    int*           shok = (int*)(CB + 36872);

    if (ctid == 0) *bcnt = 0;
    __syncthreads();  // ONCE, before chains diverge (publishes bcnt=0)

    unsigned ep = 0;
    auto CBAR = [&]() {  // intra-chain barrier: vmcnt drain + LDS epoch counter
        asm volatile("s_waitcnt vmcnt(0)" ::: "memory");
        ++ep;
        if (lane == 0)
            __hip_atomic_fetch_add(bcnt, 1u, __ATOMIC_RELEASE, __HIP_MEMORY_SCOPE_WORKGROUP);
        const unsigned tgt = 4u * ep;
        int g = 0;
        while (__hip_atomic_load(bcnt, __ATOMIC_ACQUIRE, __HIP_MEMORY_SCOPE_WORKGROUP) < tgt) {
            __builtin_amdgcn_s_sleep(1);
            if (++g > (1 << 18)) break;  // unreachable when logic correct; fail-fast
        }
    };

    const int b     = blockIdx.x;
    const int cid   = b + (ch << 8);  // chain id 0..511
    const int rb    = (b & 7) + (((b >> 3) & 1) << 3) + (ch << 4);
    const int slice = (b >> 4) & 15;
    const int r0 = rb * 32;
    const int c1 = slice * 64;    // G1 col base (HID)
    const int c2 = slice * 32;    // G2 col base (LAT)

    unsigned* czp = flags + rb * 32;
    unsigned* cgp = flags + rb * 32 + 16;

    const int fr = lane & 15;   // frag row/col index
    const int kq = lane >> 4;   // k-granule 0..3
    const int cw = w & 1;       // G2 col-half (16 cols each)
    const int kw = w >> 1;      // G2 k-half

    // ---- measured same-L2 verification; per-rb (16-member) barriers only ----
    if (ctid == 0) {
        unsigned* av    = flags + 2048 + rb * 32;
        unsigned* av2   = flags + 4096 + rb * 32;
        unsigned* trial = flags + 6144 + rb * 32;
        unsigned* vis   = flags + 8192;
        unsigned* okb   = flags + 24576;
        const unsigned magic = 0xC0DE0000u | (unsigned)cid;
        asm volatile("global_store_dword %0, %1, off sc0" :: "v"(&vis[cid * 32]), "v"(magic) : "memory");
        drain_vmem();
        __hip_atomic_fetch_add(av, 1u, __ATOMIC_RELAXED, __HIP_MEMORY_SCOPE_AGENT);
        { int g = 0; while (__hip_atomic_load(av, __ATOMIC_RELAXED, __HIP_MEMORY_SCOPE_AGENT) < 16u) { __builtin_amdgcn_s_sleep(1); if (++g > (1 << 20)) break; } }
        unsigned ok = 1;
        for (int s = 0; s < 16; ++s) {
            const int pb = (rb & 7) | (((rb >> 3) & 1) << 3) | (s << 4) | (((rb >> 4) & 1) << 8);
            unsigned v;
            asm volatile("global_load_dword %0, %1, off sc0\n\ts_waitcnt vmcnt(0)"
                         : "=v"(v) : "v"(&vis[pb * 32]) : "memory");
            ok &= (v == (0xC0DE0000u | (unsigned)pb)) ? 1u : 0u;
        }
        {   // trial round through the exact l2 flag path
            unsigned one = 1u;
            asm volatile("global_atomic_add %0, %1, off" :: "v"(trial), "v"(one) : "memory");
            int g = 0;
            while (atomic_peek_l2(trial) < 16u) {
                __builtin_amdgcn_s_sleep(1);
                if (++g > (1 << 15)) { ok = 0; break; }
            }
        }
        // consensus via proven IF path so a group can never run mixed-mode
        asm volatile("global_store_dword %0, %1, off sc0 sc1" :: "v"(&okb[cid * 32]), "v"(ok) : "memory");
        drain_vmem();
        __hip_atomic_fetch_add(av2, 1u, __ATOMIC_RELAXED, __HIP_MEMORY_SCOPE_AGENT);
        { int g = 0; while (__hip_atomic_load(av2, __ATOMIC_RELAXED, __HIP_MEMORY_SCOPE_AGENT) < 16u) { __builtin_amdgcn_s_sleep(1); if (++g > (1 << 20)) break; } }
        unsigned allok = 1;
        for (int s = 0; s < 16; ++s) {
            const int pb = (rb & 7) | (((rb >> 3) & 1) << 3) | (s << 4) | (((rb >> 4) & 1) << 8);
            unsigned v;
            asm volatile("global_load_dword %0, %1, off sc0 sc1\n\ts_waitcnt vmcnt(0)"
                         : "=v"(v) : "v"(&okb[pb * 32]) : "memory");
            allok &= v;
        }
        *shok = (int)allok;
    }
    CBAR();
    const bool l2m = (*shok != 0);

    // ---- persistent register B-fragments (128 VGPRs) ----
    bf16x8 b1r[16];  // G1: col c1+16w+fr, K=512
#pragma unroll
    for (int ks = 0; ks < 16; ++ks)
        b1r[ks] = *reinterpret_cast<const bf16x8*>(
            W1T + (size_t)(c1 + 16 * w + fr) * 512 + ks * 32 + kq * 8);

    bf16x8 b2r[16];  // G2: col c2+16cw+fr, K-half kw*512..+511
#pragma unroll
    for (int ks = 0; ks < 16; ++ks)
        b2r[ks] = *reinterpret_cast<const bf16x8*>(
            W2T + (size_t)(c2 + 16 * cw + fr) * 1024 + kw * 512 + ks * 32 + kq * 8);

    const int colg = c1 + 16 * w + fr;
    const int colk = c2 + 16 * cw + fr;
    const float b1v  = b1[colg];
    const float wlv  = wlast[colg];
    const float b2v  = b2[colk];
    const float binv = b_in[colk];

    f32x4 hr[2], ha[2];  // h, h_acc per mi (valid on kw==0 waves)

    // =========== h0 = tanh(x @ W_in + b_in) ===========
    {
#pragma unroll
        for (int i = 0; i < 4; ++i) {
            const int idx = w * 4 + i;
            const int row = idx * 2 + (lane >> 5);
            const int gam = (lane & 31) ^ (row & 7);
            gload_lds16(xb + (size_t)(r0 + row) * 256 + gam * 8,
                        (__bf16*)(CB + (size_t)idx * 1024));
        }
        bf16x8 winr[4];
#pragma unroll
        for (int ks = 0; ks < 4; ++ks)
            winr[ks] = *reinterpret_cast<const bf16x8*>(
                WinT + (size_t)colk * 256 + kw * 128 + ks * 32 + kq * 8);
        CBAR();

        f32x4 acc[2];
#pragma unroll
        for (int mi = 0; mi < 2; ++mi) acc[mi] = f32x4{0.f, 0.f, 0.f, 0.f};
#pragma unroll
        for (int ks = 0; ks < 4; ++ks) {
#pragma unroll
            for (int mi = 0; mi < 2; ++mi) {
                const int rowA = 16 * mi + fr;
                const int gk = kw * 16 + ks * 4 + kq;
                bf16x8 a = *reinterpret_cast<const bf16x8*>(
                    CB + (size_t)rowA * 512 + ((gk ^ (rowA & 7)) << 4));
                acc[mi] = __builtin_amdgcn_mfma_f32_16x16x32_bf16(a, winr[ks], acc[mi], 0, 0, 0);
            }
        }
        CBAR();
        if (kw == 1) {
#pragma unroll
            for (int mi = 0; mi < 2; ++mi)
                *reinterpret_cast<f32x4*>(SCR + ((cw * 2 + mi) * 64 + lane) * 16) = acc[mi];
        }
        CBAR();
        if (kw == 0) {
#pragma unroll
            for (int mi = 0; mi < 2; ++mi) {
                f32x4 part = *reinterpret_cast<const f32x4*>(
                    SCR + ((cw * 2 + mi) * 64 + lane) * 16);
#pragma unroll
                for (int j = 0; j < 4; ++j) {
                    const float v = tanh_fast(acc[mi][j] + part[j] + binv);
                    hr[mi][j] = v;
                    store_bf16_x(zG + (size_t)(r0 + 16 * mi + kq * 4 + j) * 512 + colk, v, l2m);
                }
            }
        }
        CBAR();  // drains all waves' stores
        if (ctid == 0) post_x(czp, l2m);
    }

    // =========== 80 dyn evaluations (20 RK4 steps x 4) ===========
    for (int it = 0; it < 80; ++it) {
        const int s4 = it >> 2, st = it & 3;
        const float t = DT * (float)s4 + ((st == 0) ? 0.f : (st == 3) ? DT : 0.5f * DT);
        const unsigned tgt = 16u * (unsigned)(it + 1);

        // ---- G1: g = tanh(z @ W1 + b1 + t*wl), this chain's 64 cols ----
        if (ctid == 0) spin_ge_t0(czp, tgt, l2m);
        CBAR();
        // stage z tile [32][512] = 32KB
#pragma unroll
        for (int i = 0; i < 8; ++i) {
            const int row = w * 8 + i;
            const int gam = lane ^ (row & 7);
            gload_lds16_x(zG + (size_t)(r0 + row) * 512 + gam * 8,
                          (__bf16*)(CB + (size_t)row * 1024), l2m);
        }
        CBAR();
        {
            f32x4 acc[2];
#pragma unroll
            for (int mi = 0; mi < 2; ++mi) acc[mi] = f32x4{0.f, 0.f, 0.f, 0.f};
#pragma unroll
            for (int ks = 0; ks < 16; ++ks) {
#pragma unroll
                for (int mi = 0; mi < 2; ++mi) {
                    const int rowA = 16 * mi + fr;
                    const int gk = ks * 4 + kq;
                    bf16x8 a = *reinterpret_cast<const bf16x8*>(
                        CB + (size_t)rowA * 1024 + ((gk ^ (rowA & 7)) << 4));
                    acc[mi] = __builtin_amdgcn_mfma_f32_16x16x32_bf16(a, b1r[ks], acc[mi], 0, 0, 0);
                }
            }
#pragma unroll
            for (int mi = 0; mi < 2; ++mi)
#pragma unroll
                for (int j = 0; j < 4; ++j) {
                    const float gv = tanh_fast(acc[mi][j] + b1v + t * wlv);
                    store_bf16_x(gG + (size_t)(r0 + 16 * mi + kq * 4 + j) * 1024 + colg, gv, l2m);
                }
        }
        CBAR();  // drains g stores
        if (ctid == 0) {
            post_x(cgp, l2m);
            spin_ge_t0(cgp, tgt, l2m);
        }
        CBAR();

        // ---- G2: k = g @ W2 + b2 (+ RK4). g tile staged in TWO 16-row halves ----
        f32x4 acc[2];
#pragma unroll
        for (int h = 0; h < 2; ++h) {
#pragma unroll
            for (int i = 0; i < 8; ++i) {
                const int idx = w * 8 + i;
                const int rl = idx >> 1;
                const int p = ((idx & 1) << 6) | lane;
                const int gam = p ^ (rl & 7);
                gload_lds16_x(gG + (size_t)(r0 + h * 16 + rl) * 1024 + gam * 8,
                              (__bf16*)(CB + (size_t)idx * 1024), l2m);
            }
            CBAR();
            acc[h] = f32x4{0.f, 0.f, 0.f, 0.f};
#pragma unroll
            for (int ks = 0; ks < 16; ++ks) {
                const int gk = kw * 64 + ks * 4 + kq;
                bf16x8 a = *reinterpret_cast<const bf16x8*>(
                    CB + (size_t)fr * 2048 + ((gk ^ (fr & 7)) << 4));
                acc[h] = __builtin_amdgcn_mfma_f32_16x16x32_bf16(a, b2r[ks], acc[h], 0, 0, 0);
            }
            CBAR();  // readers done before overwrite / scratch phase
        }
        if (kw == 1) {
#pragma unroll
            for (int mi = 0; mi < 2; ++mi)
                *reinterpret_cast<f32x4*>(SCR + ((cw * 2 + mi) * 64 + lane) * 16) = acc[mi];
        }
        CBAR();
        if (kw == 0) {
            const float wA = (st == 0 || st == 3) ? (DT / 6.0f) : (DT / 3.0f);
            const float cZ = (st < 2) ? (0.5f * DT) : DT;
#pragma unroll
            for (int mi = 0; mi < 2; ++mi) {
                f32x4 part = *reinterpret_cast<const f32x4*>(
                    SCR + ((cw * 2 + mi) * 64 + lane) * 16);
#pragma unroll
                for (int j = 0; j < 4; ++j) {
                    const float kv = acc[mi][j] + part[j] + b2v;
                    float zv;
                    if (st == 0) {
                        ha[mi][j] = hr[mi][j] + wA * kv;
                        zv = hr[mi][j] + cZ * kv;
                    } else if (st < 3) {
                        ha[mi][j] += wA * kv;
                        zv = hr[mi][j] + cZ * kv;
                    } else {
                        hr[mi][j] = ha[mi][j] + wA * kv;
                        zv = hr[mi][j];
                    }
                    store_bf16_x(zG + (size_t)(r0 + 16 * mi + kq * 4 + j) * 512 + colk, zv, l2m);
                }
            }
        }
        CBAR();  // drains z stores
        if (ctid == 0) post_x(czp, l2m);
    }

    // final h -> global (fp32; consumed by next dispatch after kernel boundary)
    if (kw == 0) {
#pragma unroll
        for (int mi = 0; mi < 2; ++mi)
#pragma unroll
            for (int j = 0; j < 4; ++j)
                hG[(size_t)(r0 + 16 * mi + kq * 4 + j) * 512 + colk] = hr[mi][j];
    }
}

// ---------------- out = h[:, :256] @ W_out + b_out (fp32) ----------------
__global__ __launch_bounds__(256)
void out_k(const float* __restrict__ h, const float* __restrict__ Wout,
           const float* __restrict__ bout, float* __restrict__ out) {
    const int col = threadIdx.x & 63;
    const int rg  = threadIdx.x >> 6;
    const int r0  = blockIdx.x * 16 + rg * 4;
    float a0 = 0.f, a1 = 0.f, a2 = 0.f, a3 = 0.f;
    for (int k = 0; k < 256; ++k) {
        const float w = Wout[k * OUTF + col];
        a0 += h[(r0 + 0) * LATF + k] * w;
        a1 += h[(r0 + 1) * LATF + k] * w;
        a2 += h[(r0 + 2) * LATF + k] * w;
        a3 += h[(r0 + 3) * LATF + k] * w;
    }
    const float b = bout[col];
    out[(r0 + 0) * OUTF + col] = a0 + b;
    out[(r0 + 1) * OUTF + col] = a1 + b;
    out[(r0 + 2) * OUTF + col] = a2 + b;
    out[(r0 + 3) * OUTF + col] = a3 + b;
}

extern "C" void kernel_launch(void* const* d_in, const int* in_sizes, int n_in,
                              void* d_out, int out_size, void* d_ws, size_t ws_size,
                              hipStream_t stream) {
    const float* x     = (const float*)d_in[0];
    const float* W_in  = (const float*)d_in[1];
    const float* b_in  = (const float*)d_in[2];
    const float* W1    = (const float*)d_in[3];   // (LAT+1, HID)
    const float* b1    = (const float*)d_in[4];
    const float* W2    = (const float*)d_in[5];   // (HID, LAT)
    const float* b2    = (const float*)d_in[6];
    const float* W_out = (const float*)d_in[7];   // (LAT/2, OUT)
    const float* b_out = (const float*)d_in[8];
    float* out = (float*)d_out;

    char* ws = (char*)d_ws;
    size_t off = 0;
    auto alloc = [&](size_t bytes) {
        void* p = ws + off;
        off += (bytes + 255) & ~(size_t)255;
        return p;
    };
    __bf16* xb   = (__bf16*)alloc((size_t)BB * INF * 2);
    __bf16* WinT = (__bf16*)alloc((size_t)LATF * INF * 2);   // [LAT][IN]
    __bf16* W1T  = (__bf16*)alloc((size_t)HIDF * LATF * 2);  // [HID][LAT]
    __bf16* W2T  = (__bf16*)alloc((size_t)LATF * HIDF * 2);  // [LAT][HID]
    float*  h    = (float*)alloc((size_t)BB * LATF * 4);
    __bf16* zbuf = (__bf16*)alloc((size_t)BB * LATF * 2);
    __bf16* gbuf = (__bf16*)alloc((size_t)BB * HIDF * 2);
    unsigned* flags = (unsigned*)alloc(163840);  // cz/cg, av/av2/trial, vis[512], okb[512]
    if (off > ws_size) return;

    (void)hipMemsetAsync(flags, 0, 163840, stream);
    prep_k<<<1408, dim3(32, 8), 0, stream>>>(x, xb, W_in, WinT, W1, W1T, W2, W2T);

    const float* w1last = W1 + (size_t)LATF * HIDF;  // row 512 of W1 (t coefficients)

    ode_persist<<<256, 512, 0, stream>>>(xb, WinT, W1T, W2T, b_in, b1, w1last, b2,
                                         zbuf, gbuf, h, flags);

    out_k<<<BB / 16, 256, 0, stream>>>(h, W_out, b_out, out);
}

// Round 16
// 597.211 us; speedup vs baseline: 4.2816x; 1.8940x over previous
//
#include <hip/hip_runtime.h>
#include <hip/hip_bf16.h>

typedef __bf16 bf16x8 __attribute__((ext_vector_type(8)));
typedef __bf16 bf16x4 __attribute__((ext_vector_type(4)));
typedef float  f32x4  __attribute__((ext_vector_type(4)));

static constexpr int BB   = 1024;
static constexpr int INF  = 256;
static constexpr int LATF = 512;
static constexpr int HIDF = 1024;
static constexpr int OUTF = 64;
static constexpr float DT = 0.05f;

// normal cached staging (weights/x; producer is a prior dispatch)
__device__ __forceinline__ void gload_lds16(const __bf16* g, __bf16* l) {
    __builtin_amdgcn_global_load_lds(
        (const __attribute__((address_space(1))) void*)g,
        (__attribute__((address_space(3))) void*)l, 16, 0, 0);
}

// exchange staging: l2 mode -> aux=1 (sc0: bypass L1, read shared XCD L2);
// fallback -> aux=17 (sc0|sc1: bypass L1+L2, read IF) — round-5 proven.
__device__ __forceinline__ void gload_lds16_x(const __bf16* g, __bf16* l, bool l2) {
    if (l2)
        __builtin_amdgcn_global_load_lds(
            (const __attribute__((address_space(1))) void*)g,
            (__attribute__((address_space(3))) void*)l, 16, 0, 1);
    else
        __builtin_amdgcn_global_load_lds(
            (const __attribute__((address_space(1))) void*)g,
            (__attribute__((address_space(3))) void*)l, 16, 0, 17);
}

// coalesced 16B exchange store: l2 mode -> sc0 (XCD L2); fallback -> write-through IF
__device__ __forceinline__ void store16_x(void* p, f32x4 v, bool l2) {
    if (l2)
        asm volatile("global_store_dwordx4 %0, %1, off sc0" :: "v"(p), "v"(v) : "memory");
    else
        asm volatile("global_store_dwordx4 %0, %1, off sc0 sc1" :: "v"(p), "v"(v) : "memory");
}

__device__ __forceinline__ void drain_vmem() {
    asm volatile("s_waitcnt vmcnt(0)" ::: "memory");
}

// l2-mode flag read THROUGH THE ATOMIC PATH (add 0, return old)
__device__ __forceinline__ unsigned atomic_peek_l2(unsigned* p) {
    unsigned v, zero = 0;
    asm volatile("global_atomic_add %0, %1, %2, off sc0\n\ts_waitcnt vmcnt(0)"
                 : "=v"(v) : "v"(p), "v"(zero) : "memory");
    return v;
}

// flag post: l2 mode -> plain atomic (local TCC); fallback -> IF agent atomic.
__device__ __forceinline__ void post_x(unsigned* p, bool l2) {
    if (l2) {
        unsigned one = 1u;
        asm volatile("global_atomic_add %0, %1, off" :: "v"(p), "v"(one) : "memory");
    } else {
        __hip_atomic_fetch_add(p, 1u, __ATOMIC_RELAXED, __HIP_MEMORY_SCOPE_AGENT);
    }
}

// tid0-only poll; short guards fail fast (bad absmax), never bench-timeout.
__device__ __forceinline__ void spin_ge_t0(unsigned* p, unsigned tgt, bool l2) {
    int guard = 0;
    if (l2) {
        while (atomic_peek_l2(p) < tgt) {
            __builtin_amdgcn_s_sleep(1);
            if (++guard > (1 << 16)) break;
        }
    } else {
        while (__hip_atomic_load(p, __ATOMIC_RELAXED, __HIP_MEMORY_SCOPE_AGENT) < tgt) {
            __builtin_amdgcn_s_sleep(1);
            if (++guard > (1 << 20)) break;
        }
    }
}

__device__ __forceinline__ float tanh_fast(float x) {
    float e = __expf(2.0f * x);
    return (e - 1.0f) / (e + 1.0f);
}

// ---------------- fused prep: x->bf16 + 3 weight transposes ----------------
__global__ __launch_bounds__(256)
void prep_k(const float* __restrict__ x, __bf16* __restrict__ xb,
            const float* __restrict__ W_in, __bf16* __restrict__ WinT,
            const float* __restrict__ W1, __bf16* __restrict__ W1T,
            const float* __restrict__ W2, __bf16* __restrict__ W2T) {
    const int b = blockIdx.x;
    const int tx = threadIdx.x, ty = threadIdx.y;
    if (b < 256) {
        const int i = b * 256 + ty * 32 + tx;
        float4 v = reinterpret_cast<const float4*>(x)[i];
        bf16x4 o;
        o[0] = (__bf16)v.x; o[1] = (__bf16)v.y; o[2] = (__bf16)v.z; o[3] = (__bf16)v.w;
        reinterpret_cast<bf16x4*>(xb)[i] = o;
        return;
    }
    const float* src; __bf16* dst; int R, C, tb;
    if (b < 384)      { src = W_in; dst = WinT; R = 256;  C = 512;  tb = b - 256; }
    else if (b < 896) { src = W1;   dst = W1T;  R = 512;  C = 1024; tb = b - 384; }
    else              { src = W2;   dst = W2T;  R = 1024; C = 512;  tb = b - 896; }
    __shared__ float tile[32][33];
    const int nbc = C / 32;
    const int c0 = (tb % nbc) * 32, r0 = (tb / nbc) * 32;
#pragma unroll
    for (int i = 0; i < 32; i += 8)
        tile[ty + i][tx] = src[(size_t)(r0 + ty + i) * C + (c0 + tx)];
    __syncthreads();
#pragma unroll
    for (int i = 0; i < 32; i += 8)
        dst[(size_t)(c0 + ty + i) * R + (r0 + tx)] = (__bf16)tile[tx][ty + i];
}

// ---------------- persistent ODE kernel (round-8 structure + coalesced stores) ----
// 256 WGs (1/CU). WG = (rb, slice): rb in [0,32) owns rows rb*32..+31; slice in
// [0,8). Exchange via measured XCD-L2 protocol (round 8, 620us). NEW: exchange
// stores go through an 8KB LDS transpose tile then out as contiguous 16B
// global_store_dwordx4 — round 8 issued 16 scattered 2-byte stores per thread
// per phase (64 wave-VMEM ops, 4x32B fragments each); now 8 wave-ops, coalesced.
__global__ __launch_bounds__(256, 1)
void ode_persist(const __bf16* __restrict__ xb, const __bf16* __restrict__ WinT,
                 const __bf16* __restrict__ W1T, const __bf16* __restrict__ W2T,
                 const float* __restrict__ b_in, const float* __restrict__ b1,
                 const float* __restrict__ wlast, const float* __restrict__ b2,
                 __bf16* __restrict__ zG, __bf16* __restrict__ gG,
                 float* __restrict__ hG, unsigned* __restrict__ flags) {
    __shared__ __align__(16) unsigned char SL[81920];  // 64KB tiles | 8KB SCR | 8KB XT
    unsigned char* const SCR = SL + 65536;
    unsigned char* const XT  = SL + 73728;
    __shared__ int sh_l2ok;

    const int bid   = blockIdx.x;
    const int rb    = (bid & 7) * 4 + ((bid >> 3) & 3);  // slices of rb share bid%8
    const int slice = bid >> 5;
    const int r0 = rb * 32;
    const int c1 = slice * 128;   // G1 col base (HID)
    const int c2 = slice * 64;    // G2 col base (LAT)

    unsigned* czp = flags + rb * 32;
    unsigned* cgp = flags + rb * 32 + 16;

    const int tid  = threadIdx.x;
    const int w    = tid >> 6;
    const int lane = tid & 63;
    const int fr   = lane & 15;
    const int kq   = lane >> 4;
    const int cw   = w & 1;
    const int kw   = w >> 1;
    const int srow = tid >> 3;      // coalesced-store row (32 rows x 8 threads)
    const int soff = tid & 7;

    // ---- measured same-L2 verification (round-8 verbatim) ----
    if (tid == 0) {
        unsigned* cvp   = flags + 1024;
        unsigned* cvp2  = flags + 1056;
        unsigned* trial = flags + 2048 + rb * 32;
        unsigned* vis   = flags + 4096;
        unsigned* okb   = flags + 12288;
        const unsigned magic = 0xC0DE0000u | (unsigned)bid;
        asm volatile("global_store_dword %0, %1, off sc0" :: "v"(&vis[bid * 32]), "v"(magic) : "memory");
        drain_vmem();
        __hip_atomic_fetch_add(cvp, 1u, __ATOMIC_RELAXED, __HIP_MEMORY_SCOPE_AGENT);
        { int g = 0; while (__hip_atomic_load(cvp, __ATOMIC_RELAXED, __HIP_MEMORY_SCOPE_AGENT) < 256u) { __builtin_amdgcn_s_sleep(1); if (++g > (1 << 20)) break; } }
        unsigned ok = 1;
        for (int s = 0; s < 8; ++s) {
            const int pb = (rb >> 2) + 8 * (rb & 3) + 32 * s;
            unsigned v;
            asm volatile("global_load_dword %0, %1, off sc0\n\ts_waitcnt vmcnt(0)"
                         : "=v"(v) : "v"(&vis[pb * 32]) : "memory");
            ok &= (v == (0xC0DE0000u | (unsigned)pb)) ? 1u : 0u;
        }
        {
            unsigned one = 1u;
            asm volatile("global_atomic_add %0, %1, off" :: "v"(trial), "v"(one) : "memory");
            int g = 0;
            while (atomic_peek_l2(trial) < 8u) {
                __builtin_amdgcn_s_sleep(1);
                if (++g > (1 << 15)) { ok = 0; break; }
            }
        }
        asm volatile("global_store_dword %0, %1, off sc0 sc1" :: "v"(&okb[bid * 32]), "v"(ok) : "memory");
        drain_vmem();
        __hip_atomic_fetch_add(cvp2, 1u, __ATOMIC_RELAXED, __HIP_MEMORY_SCOPE_AGENT);
        { int g = 0; while (__hip_atomic_load(cvp2, __ATOMIC_RELAXED, __HIP_MEMORY_SCOPE_AGENT) < 256u) { __builtin_amdgcn_s_sleep(1); if (++g > (1 << 20)) break; } }
        unsigned allok = 1;
        for (int s = 0; s < 8; ++s) {
            const int pb = (rb >> 2) + 8 * (rb & 3) + 32 * s;
            unsigned v;
            asm volatile("global_load_dword %0, %1, off sc0 sc1\n\ts_waitcnt vmcnt(0)"
                         : "=v"(v) : "v"(&okb[pb * 32]) : "memory");
            allok &= v;
        }
        sh_l2ok = (int)allok;
    }
    __syncthreads();
    const bool l2m = (sh_l2ok != 0);

    // ---- persistent register B-fragments ----
    bf16x8 b1r[2][16];  // G1: cols c1+32w+16n+fr, K=512
#pragma unroll
    for (int n = 0; n < 2; ++n)
#pragma unroll
        for (int ks = 0; ks < 16; ++ks)
            b1r[n][ks] = *reinterpret_cast<const bf16x8*>(
                W1T + (size_t)(c1 + 32 * w + 16 * n + fr) * 512 + ks * 32 + kq * 8);

    bf16x8 b2r[2][16];  // G2: cols c2+32cw+16n+fr, K-half kw*512..+511
#pragma unroll
    for (int n = 0; n < 2; ++n)
#pragma unroll
        for (int ks = 0; ks < 16; ++ks)
            b2r[n][ks] = *reinterpret_cast<const bf16x8*>(
                W2T + (size_t)(c2 + 32 * cw + 16 * n + fr) * 1024 + kw * 512 + ks * 32 + kq * 8);

    float b1v[2], wlv[2], b2v[2], binv[2];
#pragma unroll
    for (int n = 0; n < 2; ++n) {
        const int colg = c1 + 32 * w + 16 * n + fr;
        b1v[n] = b1[colg];
        wlv[n] = wlast[colg];
        const int colk = c2 + 32 * cw + 16 * n + fr;
        b2v[n] = b2[colk];
        binv[n] = b_in[colk];
    }

    f32x4 hr[2][2], ha[2][2];  // h, h_acc (meaningful on kw==0 waves)

    // coalesced z flush: ZT [32][64] bf16 (XT) -> zG rows r0..r0+31, cols c2..+63
    auto zflush = [&]() {
        f32x4 v = *reinterpret_cast<const f32x4*>(XT + (size_t)srow * 128 + soff * 16);
        store16_x(zG + (size_t)(r0 + srow) * 512 + c2 + soff * 8, v, l2m);
    };
    // coalesced g flush: GT [32][128] bf16 (XT) -> gG rows r0..r0+31, cols c1..+127
    auto gflush = [&]() {
        f32x4 v0 = *reinterpret_cast<const f32x4*>(XT + (size_t)srow * 256 + soff * 32);
        f32x4 v1 = *reinterpret_cast<const f32x4*>(XT + (size_t)srow * 256 + soff * 32 + 16);
        __bf16* p = gG + (size_t)(r0 + srow) * 1024 + c1 + soff * 16;
        store16_x(p, v0, l2m);
        store16_x(p + 8, v1, l2m);
    };

    // =========== h0 = tanh(x @ W_in + b_in) ===========
    {
#pragma unroll
        for (int i = 0; i < 4; ++i) {
            const int idx = w * 4 + i;
            const int row = idx * 2 + (lane >> 5);
            const int gam = (lane & 31) ^ (row & 7);
            gload_lds16(xb + (size_t)(r0 + row) * 256 + gam * 8,
                        (__bf16*)(SL + (size_t)idx * 1024));
        }
        bf16x8 winr[2][4];
#pragma unroll
        for (int n = 0; n < 2; ++n)
#pragma unroll
            for (int ks = 0; ks < 4; ++ks)
                winr[n][ks] = *reinterpret_cast<const bf16x8*>(
                    WinT + (size_t)(c2 + 32 * cw + 16 * n + fr) * 256 + kw * 128 + ks * 32 + kq * 8);
        __syncthreads();

        f32x4 acc[2][2];
#pragma unroll
        for (int mi = 0; mi < 2; ++mi)
#pragma unroll
            for (int n = 0; n < 2; ++n) acc[mi][n] = f32x4{0.f, 0.f, 0.f, 0.f};
#pragma unroll
        for (int ks = 0; ks < 4; ++ks) {
            bf16x8 a[2];
#pragma unroll
            for (int mi = 0; mi < 2; ++mi) {
                const int rowA = 16 * mi + fr;
                const int gk = kw * 16 + ks * 4 + kq;
                a[mi] = *reinterpret_cast<const bf16x8*>(
                    SL + (size_t)rowA * 512 + ((gk ^ (rowA & 7)) << 4));
            }
#pragma unroll
            for (int mi = 0; mi < 2; ++mi)
#pragma unroll
                for (int n = 0; n < 2; ++n)
                    acc[mi][n] = __builtin_amdgcn_mfma_f32_16x16x32_bf16(a[mi], winr[n][ks],
                                                                         acc[mi][n], 0, 0, 0);
        }
        __syncthreads();
        if (kw == 1) {
#pragma unroll
            for (int mi = 0; mi < 2; ++mi)
#pragma unroll
                for (int n = 0; n < 2; ++n)
                    *reinterpret_cast<f32x4*>(SCR + cw * 4096 + ((mi * 2 + n) * 64 + lane) * 16) =
                        acc[mi][n];
        }
        __syncthreads();
        if (kw == 0) {
#pragma unroll
            for (int mi = 0; mi < 2; ++mi)
#pragma unroll
                for (int n = 0; n < 2; ++n) {
                    f32x4 part = *reinterpret_cast<const f32x4*>(
                        SCR + cw * 4096 + ((mi * 2 + n) * 64 + lane) * 16);
#pragma unroll
                    for (int j = 0; j < 4; ++j) {
                        const float v = tanh_fast(acc[mi][n][j] + part[j] + binv[n]);
                        hr[mi][n][j] = v;
                        *reinterpret_cast<__bf16*>(
                            XT + (size_t)(16 * mi + kq * 4 + j) * 128 +
                            (32 * cw + 16 * n + fr) * 2) = (__bf16)v;
                    }
                }
        }
        __syncthreads();
        zflush();
        drain_vmem();
        __syncthreads();
        if (tid == 0) post_x(czp, l2m);
    }

    // =========== 80 dyn evaluations (20 RK4 steps x 4) ===========
    for (int it = 0; it < 80; ++it) {
        const int s4 = it >> 2, st = it & 3;
        const float t = DT * (float)s4 + ((st == 0) ? 0.f : (st == 3) ? DT : 0.5f * DT);
        const unsigned tgt = 8u * (unsigned)(it + 1);

        // ---- G1: g = tanh(z @ W1 + b1 + t*wl), this WG's 128 cols ----
        if (tid == 0) spin_ge_t0(czp, tgt, l2m);
        __syncthreads();
#pragma unroll
        for (int i = 0; i < 8; ++i) {
            const int row = w * 8 + i;
            const int gam = lane ^ (row & 7);
            gload_lds16_x(zG + (size_t)(r0 + row) * 512 + gam * 8,
                          (__bf16*)(SL + (size_t)row * 1024), l2m);
        }
        __syncthreads();
        {
            f32x4 acc[2][2];
#pragma unroll
            for (int mi = 0; mi < 2; ++mi)
#pragma unroll
                for (int n = 0; n < 2; ++n) acc[mi][n] = f32x4{0.f, 0.f, 0.f, 0.f};
#pragma unroll
            for (int ks = 0; ks < 16; ++ks) {
                bf16x8 a[2];
#pragma unroll
                for (int mi = 0; mi < 2; ++mi) {
                    const int rowA = 16 * mi + fr;
                    const int gk = ks * 4 + kq;
                    a[mi] = *reinterpret_cast<const bf16x8*>(
                        SL + (size_t)rowA * 1024 + ((gk ^ (rowA & 7)) << 4));
                }
#pragma unroll
                for (int mi = 0; mi < 2; ++mi)
#pragma unroll
                    for (int n = 0; n < 2; ++n)
                        acc[mi][n] = __builtin_amdgcn_mfma_f32_16x16x32_bf16(a[mi], b1r[n][ks],
                                                                             acc[mi][n], 0, 0, 0);
            }
            // transpose through LDS: GT[32][128] bf16
#pragma unroll
            for (int mi = 0; mi < 2; ++mi)
#pragma unroll
                for (int n = 0; n < 2; ++n)
#pragma unroll
                    for (int j = 0; j < 4; ++j) {
                        const float gv = tanh_fast(acc[mi][n][j] + b1v[n] + t * wlv[n]);
                        *reinterpret_cast<__bf16*>(
                            XT + (size_t)(16 * mi + kq * 4 + j) * 256 +
                            (32 * w + 16 * n + fr) * 2) = (__bf16)gv;
                    }
        }
        __syncthreads();
        gflush();
        drain_vmem();
        __syncthreads();
        if (tid == 0) {
            post_x(cgp, l2m);
            spin_ge_t0(cgp, tgt, l2m);
        }
        __syncthreads();
        // stage g tile [32][1024] = 64KB
#pragma unroll
        for (int i = 0; i < 16; ++i) {
            const int idx = w * 16 + i;
            const int row = idx >> 1;
            const int p = ((idx & 1) << 6) | lane;
            const int gam = p ^ (row & 7);
            gload_lds16_x(gG + (size_t)(r0 + row) * 1024 + gam * 8,
                          (__bf16*)(SL + (size_t)idx * 1024), l2m);
        }
        __syncthreads();
        {
            f32x4 acc[2][2];
#pragma unroll
            for (int mi = 0; mi < 2; ++mi)
#pragma unroll
                for (int n = 0; n < 2; ++n) acc[mi][n] = f32x4{0.f, 0.f, 0.f, 0.f};
#pragma unroll
            for (int ks = 0; ks < 16; ++ks) {
                bf16x8 a[2];
#pragma unroll
                for (int mi = 0; mi < 2; ++mi) {
                    const int rowA = 16 * mi + fr;
                    const int gk = kw * 64 + ks * 4 + kq;
                    a[mi] = *reinterpret_cast<const bf16x8*>(
                        SL + (size_t)rowA * 2048 + ((gk ^ (rowA & 7)) << 4));
                }
#pragma unroll
                for (int mi = 0; mi < 2; ++mi)
#pragma unroll
                    for (int n = 0; n < 2; ++n)
                        acc[mi][n] = __builtin_amdgcn_mfma_f32_16x16x32_bf16(a[mi], b2r[n][ks],
                                                                             acc[mi][n], 0, 0, 0);
            }
            __syncthreads();
            if (kw == 1) {
#pragma unroll
                for (int mi = 0; mi < 2; ++mi)
#pragma unroll
                    for (int n = 0; n < 2; ++n)
                        *reinterpret_cast<f32x4*>(SCR + cw * 4096 + ((mi * 2 + n) * 64 + lane) * 16) =
                            acc[mi][n];
            }
            __syncthreads();
            if (kw == 0) {
                const float wA = (st == 0 || st == 3) ? (DT / 6.0f) : (DT / 3.0f);
                const float cZ = (st < 2) ? (0.5f * DT) : DT;
#pragma unroll
                for (int mi = 0; mi < 2; ++mi)
#pragma unroll
                    for (int n = 0; n < 2; ++n) {
                        f32x4 part = *reinterpret_cast<const f32x4*>(
                            SCR + cw * 4096 + ((mi * 2 + n) * 64 + lane) * 16);
#pragma unroll
                        for (int j = 0; j < 4; ++j) {
                            const float kv = acc[mi][n][j] + part[j] + b2v[n];
                            float zv;
                            if (st == 0) {
                                ha[mi][n][j] = hr[mi][n][j] + wA * kv;
                                zv = hr[mi][n][j] + cZ * kv;
                            } else if (st < 3) {
                                ha[mi][n][j] += wA * kv;
                                zv = hr[mi][n][j] + cZ * kv;
                            } else {
                                hr[mi][n][j] = ha[mi][n][j] + wA * kv;
                                zv = hr[mi][n][j];
                            }
                            *reinterpret_cast<__bf16*>(
                                XT + (size_t)(16 * mi + kq * 4 + j) * 128 +
                                (32 * cw + 16 * n + fr) * 2) = (__bf16)zv;
                        }
                    }
            }
        }
        __syncthreads();
        zflush();
        drain_vmem();
        __syncthreads();
        if (tid == 0) post_x(czp, l2m);
    }

    // final h -> global (fp32; consumed by next dispatch after kernel boundary)
    if (kw == 0) {
#pragma unroll
        for (int mi = 0; mi < 2; ++mi)
#pragma unroll
            for (int n = 0; n < 2; ++n)
#pragma unroll
                for (int j = 0; j < 4; ++j)
                    hG[(size_t)(r0 + 16 * mi + kq * 4 + j) * 512 +
                       (c2 + 32 * cw + 16 * n + fr)] = hr[mi][n][j];
    }
}

// ---------------- out = h[:, :256] @ W_out + b_out (fp32) ----------------
__global__ __launch_bounds__(256)
void out_k(const float* __restrict__ h, const float* __restrict__ Wout,
           const float* __restrict__ bout, float* __restrict__ out) {
    const int col = threadIdx.x & 63;
    const int rg  = threadIdx.x >> 6;
    const int r0  = blockIdx.x * 16 + rg * 4;
    float a0 = 0.f, a1 = 0.f, a2 = 0.f, a3 = 0.f;
    for (int k = 0; k < 256; ++k) {
        const float w = Wout[k * OUTF + col];
        a0 += h[(r0 + 0) * LATF + k] * w;
        a1 += h[(r0 + 1) * LATF + k] * w;
        a2 += h[(r0 + 2) * LATF + k] * w;
        a3 += h[(r0 + 3) * LATF + k] * w;
    }
    const float b = bout[col];
    out[(r0 + 0) * OUTF + col] = a0 + b;
    out[(r0 + 1) * OUTF + col] = a1 + b;
    out[(r0 + 2) * OUTF + col] = a2 + b;
    out[(r0 + 3) * OUTF + col] = a3 + b;
}

extern "C" void kernel_launch(void* const* d_in, const int* in_sizes, int n_in,
                              void* d_out, int out_size, void* d_ws, size_t ws_size,
                              hipStream_t stream) {
    const float* x     = (const float*)d_in[0];
    const float* W_in  = (const float*)d_in[1];
    const float* b_in  = (const float*)d_in[2];
    const float* W1    = (const float*)d_in[3];   // (LAT+1, HID)
    const float* b1    = (const float*)d_in[4];
    const float* W2    = (const float*)d_in[5];   // (HID, LAT)
    const float* b2    = (const float*)d_in[6];
    const float* W_out = (const float*)d_in[7];   // (LAT/2, OUT)
    const float* b_out = (const float*)d_in[8];
    float* out = (float*)d_out;

    char* ws = (char*)d_ws;
    size_t off = 0;
    auto alloc = [&](size_t bytes) {
        void* p = ws + off;
        off += (bytes + 255) & ~(size_t)255;
        return p;
    };
    __bf16* xb   = (__bf16*)alloc((size_t)BB * INF * 2);
    __bf16* WinT = (__bf16*)alloc((size_t)LATF * INF * 2);   // [LAT][IN]
    __bf16* W1T  = (__bf16*)alloc((size_t)HIDF * LATF * 2);  // [HID][LAT]
    __bf16* W2T  = (__bf16*)alloc((size_t)LATF * HIDF * 2);  // [LAT][HID]
    float*  h    = (float*)alloc((size_t)BB * LATF * 4);
    __bf16* zbuf = (__bf16*)alloc((size_t)BB * LATF * 2);
    __bf16* gbuf = (__bf16*)alloc((size_t)BB * HIDF * 2);
    unsigned* flags = (unsigned*)alloc(98304);
    if (off > ws_size) return;

    (void)hipMemsetAsync(flags, 0, 98304, stream);
    prep_k<<<1408, dim3(32, 8), 0, stream>>>(x, xb, W_in, WinT, W1, W1T, W2, W2T);

    const float* w1last = W1 + (size_t)LATF * HIDF;  // row 512 of W1 (t coefficients)

    ode_persist<<<256, 256, 0, stream>>>(xb, WinT, W1T, W2T, b_in, b1, w1last, b2,
                                         zbuf, gbuf, h, flags);

    out_k<<<BB / 16, 256, 0, stream>>>(h, W_out, b_out, out);
}